// Round 7
// baseline (168.056 us; speedup 1.0000x reference)
//
#include <hip/hip_runtime.h>
#include <stdint.h>

// ---------- types ----------
typedef __bf16 bf16x8 __attribute__((ext_vector_type(8)));
typedef float f32x4 __attribute__((ext_vector_type(4)));
typedef float float4v __attribute__((ext_vector_type(4)));
typedef unsigned short u16x8 __attribute__((ext_vector_type(8)));

// round-to-nearest-even fp32 -> bf16
__device__ __forceinline__ unsigned short f2bf(float f) {
    unsigned u = __float_as_uint(f);
    u += 0x7fffu + ((u >> 16) & 1u);
    return (unsigned short)(u >> 16);
}

// fast stable softplus: max(x,0) + log(1+exp(-|x|))
__device__ __forceinline__ float softplus(float x) {
    return fmaxf(x, 0.0f) + __logf(1.0f + __expf(-fabsf(x)));
}

// async global->LDS, 16B per lane (gfx950). LDS dest must be wave-uniform
// base + lane*16 (lane-ordered, contiguous).
__device__ __forceinline__ void gl_lds16(const void* gptr, void* lptr) {
    auto g = reinterpret_cast<const __attribute__((address_space(1))) void*>(
        reinterpret_cast<uintptr_t>(gptr));
    auto l = reinterpret_cast<__attribute__((address_space(3))) void*>(
        reinterpret_cast<uintptr_t>(lptr));
    __builtin_amdgcn_global_load_lds(g, l, 16, 0, 0);
}

// ---------- fused prep ----------
// input f32 -> bf16 row-major; w = mu + softplus(rho)*eps -> bf16 in
// MFMA-FRAGMENT-TILED layout [N/16][K/32][16 n][32 k] (n-major inner) so the
// GEMM can load B-fragments as single coalesced 16B/lane global loads
// (R5 lesson: row-major direct-B is 16-way uncoalesced; this layout makes a
// wave's B-frag one contiguous 1 KB block).
__global__ void prep_kernel(const float* __restrict__ in,
                            const float* __restrict__ mu,
                            const float* __restrict__ rho,
                            const float* __restrict__ eps,
                            unsigned short* __restrict__ in_bf,
                            unsigned short* __restrict__ w_bf,
                            int nIn8, int nW8, int K) {
    int i = blockIdx.x * blockDim.x + threadIdx.x;
    if (i < nIn8) {
        const float4v* p = (const float4v*)in + (size_t)i * 2;
        float4v a = p[0], b = p[1];
        u16x8 r;
        r[0] = f2bf(a[0]); r[1] = f2bf(a[1]); r[2] = f2bf(a[2]); r[3] = f2bf(a[3]);
        r[4] = f2bf(b[0]); r[5] = f2bf(b[1]); r[6] = f2bf(b[2]); r[7] = f2bf(b[3]);
        ((u16x8*)in_bf)[i] = r;
    } else {
        int j = i - nIn8;
        if (j >= nW8) return;
        const float4v* pm = (const float4v*)mu  + (size_t)j * 2;
        const float4v* pr = (const float4v*)rho + (size_t)j * 2;
        const float4v* pe = (const float4v*)eps + (size_t)j * 2;
        float4v m0 = pm[0], m1 = pm[1];
        float4v r0 = pr[0], r1 = pr[1];
        float4v e0 = pe[0], e1 = pe[1];
        u16x8 r;
        r[0] = f2bf(m0[0] + softplus(r0[0]) * e0[0]);
        r[1] = f2bf(m0[1] + softplus(r0[1]) * e0[1]);
        r[2] = f2bf(m0[2] + softplus(r0[2]) * e0[2]);
        r[3] = f2bf(m0[3] + softplus(r0[3]) * e0[3]);
        r[4] = f2bf(m1[0] + softplus(r1[0]) * e1[0]);
        r[5] = f2bf(m1[1] + softplus(r1[1]) * e1[1]);
        r[6] = f2bf(m1[2] + softplus(r1[2]) * e1[2]);
        r[7] = f2bf(m1[3] + softplus(r1[3]) * e1[3]);
        // fragment-tiled destination
        int kg  = K >> 3;              // 8-groups per row
        int o   = j / kg;              // output-channel row n
        int ic  = (j - o * kg) * 8;    // col (k) of this 8-group
        size_t dst = ((size_t)(o >> 4) * (K >> 5) + (ic >> 5)) * 1024
                   + (o & 15) * 32 + (ic & 31);
        *(u16x8*)(w_bf + dst) = r;
    }
}

// ---------- GEMM: C[M,N] = A[M,K]*W^T + bias, bf16 in / f32 out -----------
// R7 = R3's winning loop (512 thr, 8 waves 2x4, wave-tile 64x32, dbuf LDS,
// gl_lds16, 1 barrier/iter, XOR swizzle) with B REMOVED FROM LDS:
// B-fragments load direct from the fragment-tiled w_bf (one coalesced
// dwordx4 per frag), prefetched one iter ahead into registers.
// Per CU-iter: LDS 2816 -> ~1792 cyc at UNCHANGED 16 waves/CU (R6 showed
// both matter: low LDS traffic at 8 waves/CU lost to latency).
#define BM 128
#define BN 128
#define BK 64

__global__ __launch_bounds__(512, 4)
void gemm_bt_kernel(const unsigned short* __restrict__ A,    // [M,K] bf16
                    const unsigned short* __restrict__ Bt,   // frag-tiled W
                    const float* __restrict__ bias,          // [N]
                    float* __restrict__ C,                   // [M,N] f32
                    int M, int N, int K) {
    __shared__ unsigned short lds_a[2][BM * BK];   // 2 x 16 KB (A only)

    const int t      = threadIdx.x;
    const int lane   = t & 63;
    const int wave   = t >> 6;          // 0..7
    const int lane16 = lane & 15;
    const int quad   = lane >> 4;       // 0..3
    const int wm     = wave & 1;        // wave row: 0..1 (64 rows each)
    const int wn     = wave >> 1;       // wave col: 0..3 (32 cols each)

    const int m0 = blockIdx.y * BM;
    const int n0 = blockIdx.x * BN;

    // A staging: 1024 16B-chunks, 512 threads -> 2 chunks each.
    // chunk c -> LDS slot c (row=c>>3, pkg=c&7); global kg = pkg ^ (row&7)
    const int r1  = t >> 3;                 // rows 0..63
    const int pkg = t & 7;
    const int g1  = (pkg ^ (r1 & 7)) * 8;
    const int r2  = r1 + 64;                // rows 64..127
    const int g2  = (pkg ^ (r2 & 7)) * 8;

    const unsigned short* Ab = A + (size_t)m0 * K;

    // B fragment-tile base pointers (ni = 0,1): tile row nt = n>>4,
    // lane offset lane16*32 + quad*8 inside the 1024-elem tile.
    const int kb_per_row = K >> 5;          // k-blocks per tile row
    const unsigned short* pB[2];
#pragma unroll
    for (int ni = 0; ni < 2; ni++)
        pB[ni] = Bt + ((size_t)((n0 + wn * 32 + ni * 16) >> 4) * kb_per_row) * 1024
                    + lane16 * 32 + quad * 8;

    f32x4 acc[4][2] = {};
    const int sw  = lane16 & 7;   // A read-side swizzle key
    const int nit = K / BK;       // 32 (even)

    auto stageA = [&](int buf, int k0) {
        gl_lds16(Ab + (size_t)r1 * K + k0 + g1, &lds_a[buf][t * 8]);
        gl_lds16(Ab + (size_t)r2 * K + k0 + g2, &lds_a[buf][4096 + t * 8]);
    };
    auto loadB = [&](bf16x8 (&dst)[2][2], int it) {
        const int kb = it * 2;              // two 32-k blocks per BK=64 iter
#pragma unroll
        for (int ch = 0; ch < 2; ch++)
#pragma unroll
            for (int ni = 0; ni < 2; ni++)
                dst[ch][ni] = *(const bf16x8*)(pB[ni] + (size_t)(kb + ch) * 1024);
    };

    bf16x8 bX[2][2], bY[2][2];

    // prologue
    loadB(bX, 0);
    stageA(0, 0);
    __syncthreads();

    auto body = [&](int cur, int it, bf16x8 (&bcur)[2][2], bf16x8 (&bnxt)[2][2]) {
        // (1) prefetch next iter's B-frags (coalesced, in flight across MFMA)
        if (it + 1 < nit) loadB(bnxt, it + 1);
        // (2) A fragment reads from current LDS buffer (8 ds_read_b128)
        bf16x8 af[2][4];
#pragma unroll
        for (int ch = 0; ch < 2; ch++) {
            const int pk = ((ch * 4 + quad) ^ sw) * 8;
#pragma unroll
            for (int mi = 0; mi < 4; mi++)
                af[ch][mi] = *(const bf16x8*)(&lds_a[cur][0] +
                               (wm * 64 + mi * 16 + lane16) * BK + pk);
        }
        // (3) async-stage next A tile into other buffer
        if (it + 1 < nit) stageA(cur ^ 1, (it + 1) * BK);
        // (4) 16 MFMAs
#pragma unroll
        for (int ch = 0; ch < 2; ch++)
#pragma unroll
            for (int mi = 0; mi < 4; mi++)
#pragma unroll
                for (int ni = 0; ni < 2; ni++)
                    acc[mi][ni] = __builtin_amdgcn_mfma_f32_16x16x32_bf16(
                        af[ch][mi], bcur[ch][ni], acc[mi][ni], 0, 0, 0);
        // (5) single barrier (drains staging, releases current buffer)
        __syncthreads();
    };

    for (int it = 0; it < nit; it += 2) {
        body(0, it,     bX, bY);
        body(1, it + 1, bY, bX);
    }

    // epilogue: C/D layout col=lane&15, row=quad*4+reg (m89-verified)
    float bv[2];
#pragma unroll
    for (int ni = 0; ni < 2; ni++)
        bv[ni] = bias[n0 + wn * 32 + ni * 16 + lane16];

#pragma unroll
    for (int mi = 0; mi < 4; mi++) {
        const int rbase = m0 + wm * 64 + mi * 16 + quad * 4;
#pragma unroll
        for (int ni = 0; ni < 2; ni++) {
            const int col = n0 + wn * 32 + ni * 16 + lane16;
#pragma unroll
            for (int r = 0; r < 4; r++)
                C[(size_t)(rbase + r) * N + col] = acc[mi][ni][r] + bv[ni];
        }
    }
}

extern "C" void kernel_launch(void* const* d_in, const int* in_sizes, int n_in,
                              void* d_out, int out_size, void* d_ws, size_t ws_size,
                              hipStream_t stream) {
    const float* input = (const float*)d_in[0];
    const float* mu    = (const float*)d_in[1];
    const float* rho   = (const float*)d_in[2];
    const float* eps   = (const float*)d_in[3];
    const float* bias  = (const float*)d_in[4];
    float* out = (float*)d_out;

    const int OUT = in_sizes[4];              // 2048
    const int IN  = in_sizes[1] / OUT;        // 2048
    const int M   = in_sizes[0] / IN;         // 4096

    unsigned short* in_bf = (unsigned short*)d_ws;                 // M*IN bf16
    unsigned short* w_bf  = in_bf + (size_t)M * IN;                // OUT*IN bf16 (tiled)

    const int nIn8 = (M * IN) / 8;
    const int nW8  = (OUT * IN) / 8;
    prep_kernel<<<dim3((nIn8 + nW8 + 255) / 256), 256, 0, stream>>>(
        input, mu, rho, eps, in_bf, w_bf, nIn8, nW8, IN);

    gemm_bt_kernel<<<dim3(OUT / BN, M / BM), 512, 0, stream>>>(
        in_bf, w_bf, bias, out, M, OUT, IN);
}

// Round 8
// 160.781 us; speedup vs baseline: 1.0452x; 1.0452x over previous
//
#include <hip/hip_runtime.h>
#include <stdint.h>

// ======================= R8 = exact revert to R3 (best) =====================
// R3: GEMM 40.3us (~853 TF), total ~160us. Measured 93% of the LDS-read-pipe
// floor (2816 cyc/CU-iter model). Constraint web (R4-R7 falsifications):
//  - fragments cannot come direct from global (R5: uncoalesced 4KB lane
//    stride; R7: even coalesced tiled-B adds VMEM into the barrier drain);
//  - wave-tile 64x64 halves LDS traffic but also halves occupancy -> worse
//    (R6: 8 waves/CU is latency-exposed);
//  - M*N area (8.4M) -> grid 512 -> 2 blocks/CU; 16 waves/CU forces 8-wave
//    blocks -> wave-tile 64x32. R3 is the joint optimum of this family.

// ---------- types ----------
typedef __bf16 bf16x8 __attribute__((ext_vector_type(8)));
typedef float f32x4 __attribute__((ext_vector_type(4)));
typedef float float4v __attribute__((ext_vector_type(4)));
typedef unsigned short u16x8 __attribute__((ext_vector_type(8)));

// round-to-nearest-even fp32 -> bf16
__device__ __forceinline__ unsigned short f2bf(float f) {
    unsigned u = __float_as_uint(f);
    u += 0x7fffu + ((u >> 16) & 1u);
    return (unsigned short)(u >> 16);
}

// fast stable softplus: max(x,0) + log(1+exp(-|x|))
__device__ __forceinline__ float softplus(float x) {
    return fmaxf(x, 0.0f) + __logf(1.0f + __expf(-fabsf(x)));
}

// async global->LDS, 16B per lane (gfx950). LDS dest must be wave-uniform
// base + lane*16 (lane-ordered, contiguous).
__device__ __forceinline__ void gl_lds16(const void* gptr, void* lptr) {
    auto g = reinterpret_cast<const __attribute__((address_space(1))) void*>(
        reinterpret_cast<uintptr_t>(gptr));
    auto l = reinterpret_cast<__attribute__((address_space(3))) void*>(
        reinterpret_cast<uintptr_t>(lptr));
    __builtin_amdgcn_global_load_lds(g, l, 16, 0, 0);
}

// ---------- fused prep: input f32->bf16  AND  w = mu + softplus(rho)*eps ----
__global__ void prep_kernel(const float* __restrict__ in,
                            const float* __restrict__ mu,
                            const float* __restrict__ rho,
                            const float* __restrict__ eps,
                            unsigned short* __restrict__ in_bf,
                            unsigned short* __restrict__ w_bf,
                            int nIn8, int nW8) {
    int i = blockIdx.x * blockDim.x + threadIdx.x;
    if (i < nIn8) {
        const float4v* p = (const float4v*)in + (size_t)i * 2;
        float4v a = p[0], b = p[1];
        u16x8 r;
        r[0] = f2bf(a[0]); r[1] = f2bf(a[1]); r[2] = f2bf(a[2]); r[3] = f2bf(a[3]);
        r[4] = f2bf(b[0]); r[5] = f2bf(b[1]); r[6] = f2bf(b[2]); r[7] = f2bf(b[3]);
        ((u16x8*)in_bf)[i] = r;
    } else {
        int j = i - nIn8;
        if (j >= nW8) return;
        const float4v* pm = (const float4v*)mu  + (size_t)j * 2;
        const float4v* pr = (const float4v*)rho + (size_t)j * 2;
        const float4v* pe = (const float4v*)eps + (size_t)j * 2;
        float4v m0 = pm[0], m1 = pm[1];
        float4v r0 = pr[0], r1 = pr[1];
        float4v e0 = pe[0], e1 = pe[1];
        u16x8 r;
        r[0] = f2bf(m0[0] + softplus(r0[0]) * e0[0]);
        r[1] = f2bf(m0[1] + softplus(r0[1]) * e0[1]);
        r[2] = f2bf(m0[2] + softplus(r0[2]) * e0[2]);
        r[3] = f2bf(m0[3] + softplus(r0[3]) * e0[3]);
        r[4] = f2bf(m1[0] + softplus(r1[0]) * e1[0]);
        r[5] = f2bf(m1[1] + softplus(r1[1]) * e1[1]);
        r[6] = f2bf(m1[2] + softplus(r1[2]) * e1[2]);
        r[7] = f2bf(m1[3] + softplus(r1[3]) * e1[3]);
        ((u16x8*)w_bf)[j] = r;
    }
}

// ---------- GEMM: C[M,N] = A[M,K] * B[N,K]^T + bias, bf16 in / f32 out -----
// 128x128 tile, BK=64, 512 threads = 8 waves 2(m)x4(n), wave tile 64x32.
// Double-buffered LDS, ONE barrier per K-iter; gl_lds16 staging issued after
// the fragment ds_reads so the barrier's vmcnt(0) drain lands after the
// MFMA block. XOR-swizzled k-groups: 0 bank conflicts (measured R2/R3).
#define BM 128
#define BN 128
#define BK 64

__global__ __launch_bounds__(512, 4)
void gemm_bt_kernel(const unsigned short* __restrict__ A,   // [M,K] bf16
                    const unsigned short* __restrict__ B,   // [N,K] bf16
                    const float* __restrict__ bias,         // [N]
                    float* __restrict__ C,                  // [M,N] f32
                    int M, int N, int K) {
    __shared__ unsigned short lds_a[2][BM * BK];   // 2 x 16 KB
    __shared__ unsigned short lds_b[2][BN * BK];   // 2 x 16 KB

    const int t      = threadIdx.x;
    const int lane   = t & 63;
    const int wave   = t >> 6;          // 0..7
    const int lane16 = lane & 15;
    const int quad   = lane >> 4;       // 0..3
    const int wm     = wave & 1;        // wave row: 0..1 (64 rows each)
    const int wn     = wave >> 1;       // wave col: 0..3 (32 cols each)

    const int m0 = blockIdx.y * BM;
    const int n0 = blockIdx.x * BN;

    // staging: 1024 16B-chunks per tile, 512 threads -> 2 chunks each.
    // chunk c -> LDS slot c (row=c>>3, pkg=c&7); global kg = pkg ^ (row&7)
    const int r1   = t >> 3;                 // rows 0..63
    const int pkg  = t & 7;
    const int g1   = (pkg ^ (r1 & 7)) * 8;
    const int r2   = r1 + 64;                // rows 64..127
    const int g2   = (pkg ^ (r2 & 7)) * 8;

    const unsigned short* Ab = A + (size_t)m0 * K;
    const unsigned short* Bb = B + (size_t)n0 * K;

    f32x4 acc[4][2] = {};
    const int sw = lane16 & 7;   // read-side swizzle key

    auto stage = [&](int buf, int k0) {
        gl_lds16(Ab + (size_t)r1 * K + k0 + g1, &lds_a[buf][t * 8]);
        gl_lds16(Ab + (size_t)r2 * K + k0 + g2, &lds_a[buf][4096 + t * 8]);
        gl_lds16(Bb + (size_t)r1 * K + k0 + g1, &lds_b[buf][t * 8]);
        gl_lds16(Bb + (size_t)r2 * K + k0 + g2, &lds_b[buf][4096 + t * 8]);
    };

    const int nit = K / BK;       // 32 (even)
    stage(0, 0);
    __syncthreads();              // drain prologue staging

    auto body = [&](int cur, int it) {
        const unsigned short* la = lds_a[cur];
        const unsigned short* lb = lds_b[cur];
        // (1) hoist ALL fragment reads from current buffer
        bf16x8 af[2][4], bfr[2][2];
#pragma unroll
        for (int ch = 0; ch < 2; ch++) {
            const int pk = ((ch * 4 + quad) ^ sw) * 8;
#pragma unroll
            for (int mi = 0; mi < 4; mi++)
                af[ch][mi] = *(const bf16x8*)(la + (wm * 64 + mi * 16 + lane16) * BK + pk);
#pragma unroll
            for (int ni = 0; ni < 2; ni++)
                bfr[ch][ni] = *(const bf16x8*)(lb + (wn * 32 + ni * 16 + lane16) * BK + pk);
        }
        // (2) async-stage NEXT tile into the other buffer (no alias with reads)
        if (it + 1 < nit) stage(cur ^ 1, (it + 1) * BK);
        // (3) MFMAs — vmcnt drain at the barrier lands after these
#pragma unroll
        for (int ch = 0; ch < 2; ch++)
#pragma unroll
            for (int mi = 0; mi < 4; mi++)
#pragma unroll
                for (int ni = 0; ni < 2; ni++)
                    acc[mi][ni] = __builtin_amdgcn_mfma_f32_16x16x32_bf16(
                        af[ch][mi], bfr[ch][ni], acc[mi][ni], 0, 0, 0);
        // (4) single barrier: next-staging drained AND current buffer released
        __syncthreads();
    };

    for (int it = 0; it < nit; it += 2) {
        body(0, it);
        body(1, it + 1);
    }

    // epilogue: C/D layout col=lane&15, row=quad*4+reg (m89-verified)
    float bv[2];
#pragma unroll
    for (int ni = 0; ni < 2; ni++)
        bv[ni] = bias[n0 + wn * 32 + ni * 16 + lane16];

#pragma unroll
    for (int mi = 0; mi < 4; mi++) {
        const int rbase = m0 + wm * 64 + mi * 16 + quad * 4;
#pragma unroll
        for (int ni = 0; ni < 2; ni++) {
            const int col = n0 + wn * 32 + ni * 16 + lane16;
#pragma unroll
            for (int r = 0; r < 4; r++)
                C[(size_t)(rbase + r) * N + col] = acc[mi][ni][r] + bv[ni];
        }
    }
}

extern "C" void kernel_launch(void* const* d_in, const int* in_sizes, int n_in,
                              void* d_out, int out_size, void* d_ws, size_t ws_size,
                              hipStream_t stream) {
    const float* input = (const float*)d_in[0];
    const float* mu    = (const float*)d_in[1];
    const float* rho   = (const float*)d_in[2];
    const float* eps   = (const float*)d_in[3];
    const float* bias  = (const float*)d_in[4];
    float* out = (float*)d_out;

    const int OUT = in_sizes[4];              // 2048
    const int IN  = in_sizes[1] / OUT;        // 2048
    const int M   = in_sizes[0] / IN;         // 4096

    unsigned short* in_bf = (unsigned short*)d_ws;                 // M*IN bf16
    unsigned short* w_bf  = in_bf + (size_t)M * IN;                // OUT*IN bf16

    const int nIn8 = (M * IN) / 8;
    const int nW8  = (OUT * IN) / 8;
    prep_kernel<<<dim3((nIn8 + nW8 + 255) / 256), 256, 0, stream>>>(
        input, mu, rho, eps, in_bf, w_bf, nIn8, nW8);

    gemm_bt_kernel<<<dim3(OUT / BN, M / BM), 512, 0, stream>>>(
        in_bf, w_bf, bias, out, M, OUT, IN);
}